// Round 6
// baseline (126.101 us; speedup 1.0000x reference)
//
#include <hip/hip_runtime.h>

#define KP    96      // K=85 padded to 96 = 12 octets
#define NF    16
#define NCOL  117     // 16 + 85 + 16 output columns
#define RPAD  120     // LDS row stride (16B-aligned)
#define PBLK  (KP * NF)   // 1536 floats per partial block
#define NPB   32      // points per block-iteration (k1)

// ---------------------------------------------------------------------------
// Kernel 1: wave-per-k-octet partial QF accumulation. (UNCHANGED from R5.)
// ---------------------------------------------------------------------------
__global__ __launch_bounds__(768, 3) void k1_partial(
    const float* __restrict__ X, const float* __restrict__ F,
    const float* __restrict__ QX, const float* __restrict__ omegaD,
    int K, int nchunk, float* __restrict__ partial)
{
    __shared__ __align__(16) float red[12 * 2 * 64];   // 6 KB

    const int tid  = threadIdx.x;
    const int lane = tid & 63;
    const int oct  = __builtin_amdgcn_readfirstlane(tid >> 6);  // wave id 0..11
    const int fh   = lane >> 5;     // f-half
    const int pl   = lane & 31;     // point lane

    float4 qreg[8];
#pragma unroll
    for (int kk = 0; kk < 8; ++kk) {
        const int k = oct * 8 + kk;
        float4 v = make_float4(1.0e4f, 1.0e4f, 1.0e4f, -1.0f);  // pad -> e=0
        if (k < K) {
            v.x = QX[k * 3 + 0];
            v.y = QX[k * 3 + 1];
            v.z = QX[k * 3 + 2];
            const float w = omegaD[k];
            v.w = 1.0f / (w * w);
        }
        qreg[kk] = v;
    }

    float acc[8][8];
#pragma unroll
    for (int a2 = 0; a2 < 8; ++a2)
#pragma unroll
        for (int b2 = 0; b2 < 8; ++b2) acc[a2][b2] = 0.f;

    int pb = blockIdx.x;
    float x0 = 0.f, x1 = 0.f, x2 = 0.f;
    float4 fa = make_float4(0.f, 0.f, 0.f, 0.f), fb = fa;
    if (pb < nchunk) {
        const int p = pb * NPB + pl;
        x0 = X[p * 3 + 0]; x1 = X[p * 3 + 1]; x2 = X[p * 3 + 2];
        fa = *reinterpret_cast<const float4*>(&F[(size_t)p * NF + 8 * fh]);
        fb = *reinterpret_cast<const float4*>(&F[(size_t)p * NF + 8 * fh + 4]);
    }
    while (pb < nchunk) {
        const int pn = pb + gridDim.x;
        float nx0 = 0.f, nx1 = 0.f, nx2 = 0.f;
        float4 nfa = make_float4(0.f, 0.f, 0.f, 0.f), nfb = nfa;
        if (pn < nchunk) {
            const int p = pn * NPB + pl;
            nx0 = X[p * 3 + 0]; nx1 = X[p * 3 + 1]; nx2 = X[p * 3 + 2];
            nfa = *reinterpret_cast<const float4*>(&F[(size_t)p * NF + 8 * fh]);
            nfb = *reinterpret_cast<const float4*>(&F[(size_t)p * NF + 8 * fh + 4]);
        }

        float e[8];
#pragma unroll
        for (int kk = 0; kk < 8; ++kk) {
            const float4 q = qreg[kk];
            const float dx = x0 - q.x;
            const float dy = x1 - q.y;
            const float dz = x2 - q.z;
            e[kk] = __expf((dx * dx + dy * dy + dz * dz) * q.w);
        }
        const float fv[8] = {fa.x, fa.y, fa.z, fa.w, fb.x, fb.y, fb.z, fb.w};
#pragma unroll
        for (int kk = 0; kk < 8; ++kk)
#pragma unroll
            for (int u = 0; u < 8; ++u) acc[kk][u] += e[kk] * fv[u];

        x0 = nx0; x1 = nx1; x2 = nx2; fa = nfa; fb = nfb;
        pb = pn;
    }

#pragma unroll
    for (int m = 1; m <= 16; m <<= 1) {
#pragma unroll
        for (int a2 = 0; a2 < 8; ++a2)
#pragma unroll
            for (int b2 = 0; b2 < 8; ++b2)
                acc[a2][b2] += __shfl_xor(acc[a2][b2], m);
    }
    if (pl == 0) {
        float* rp = &red[oct * 128 + fh * 64];
#pragma unroll
        for (int a2 = 0; a2 < 8; ++a2) {
            *reinterpret_cast<float4*>(&rp[a2 * 8]) =
                make_float4(acc[a2][0], acc[a2][1], acc[a2][2], acc[a2][3]);
            *reinterpret_cast<float4*>(&rp[a2 * 8 + 4]) =
                make_float4(acc[a2][4], acc[a2][5], acc[a2][6], acc[a2][7]);
        }
    }
    __syncthreads();
    float* pbase = partial + (size_t)blockIdx.x * PBLK;
    for (int idx = tid; idx < PBLK; idx += 768) {
        const int o2 = idx >> 7;          // octet
        const int r  = idx & 127;
        const int kk = r >> 4;
        const int f  = r & 15;
        pbase[idx] = red[o2 * 128 + (f >> 3) * 64 + kk * 8 + (f & 7)];
    }
}

// ---------------------------------------------------------------------------
// Kernel 1.5: fixed-order reduction of partials -> QF (applies omegaF).
// (UNCHANGED.)
// ---------------------------------------------------------------------------
__global__ __launch_bounds__(256) void k1_reduce(
    const float* __restrict__ partial, const float* __restrict__ omegaF,
    int nb, float* __restrict__ QF)
{
    const int k   = blockIdx.x;
    const int tid = threadIdx.x;
    const int f = tid & 15, g = tid >> 4;
    float s = 0.f;
    for (int b = g; b < nb; b += 16)
        s += partial[(size_t)b * PBLK + k * NF + f];
    __shared__ float red[16][17];
    red[g][f] = s;
    __syncthreads();
    if (tid < 16) {
        float t = 0.f;
#pragma unroll
        for (int g2 = 0; g2 < 16; ++g2) t += red[g2][tid];
        QF[k * NF + tid] = t * omegaF[tid];
    }
}

// ---------------------------------------------------------------------------
// Kernel 2 (REWRITTEN): QF in registers, zero LDS reads in the k-loop.
// 256 threads = 16 k-lanes (q, lane bits 0..3) x 16 points (pp). Lane q owns
// QF rows k = q + 16j (j<6; 96 VGPR, loaded once). Per sub-batch of 16
// points: t = fr.qr (16 FMA), g += t*qr (16 FMA) per owned k; t -> LDS row
// buffer (b32, <=2-way banks); g reduced via 4-step shfl_xor butterfly over
// q bits. Rows [16][120] flushed with coalesced b32 stores.
// ---------------------------------------------------------------------------
__global__ __launch_bounds__(256, 3) void k2_out(
    const float* __restrict__ F, const float* __restrict__ QFb,
    float* __restrict__ out)
{
    __shared__ __align__(16) float row[16 * RPAD];   // 7.5 KB staged rows

    const int tid = threadIdx.x;
    const int q   = tid & 15;   // k-lane
    const int pp  = tid >> 4;   // point slot 0..15

    // lane q's QF rows: k = q + 16j, j = 0..5 (zero-padded past K=85)
    float qreg[6][NF];
#pragma unroll
    for (int j = 0; j < 6; ++j) {
        const int k = q + 16 * j;
        if (k < 85) {
            const float4* qv = reinterpret_cast<const float4*>(QFb + (size_t)k * NF);
#pragma unroll
            for (int u = 0; u < 4; ++u) {
                const float4 t4 = qv[u];
                qreg[j][4 * u + 0] = t4.x; qreg[j][4 * u + 1] = t4.y;
                qreg[j][4 * u + 2] = t4.z; qreg[j][4 * u + 3] = t4.w;
            }
        } else {
#pragma unroll
            for (int u = 0; u < NF; ++u) qreg[j][u] = 0.f;
        }
    }

    const int chunk = blockIdx.x * 256;

    for (int sb = 0; sb < 16; ++sb) {
        const int p = chunk + sb * 16 + pp;

        float fr[NF];
        float4 fr4[4];
        {
            const float4* Fv = reinterpret_cast<const float4*>(F + (size_t)p * NF);
#pragma unroll
            for (int u = 0; u < 4; ++u) {
                const float4 t4 = Fv[u];
                fr4[u] = t4;
                fr[4 * u + 0] = t4.x; fr[4 * u + 1] = t4.y;
                fr[4 * u + 2] = t4.z; fr[4 * u + 3] = t4.w;
            }
        }
        // F section: lanes q<4 write one float4 each (RPAD=120 keeps 16B align)
        if (q < 4)
            *reinterpret_cast<float4*>(&row[pp * RPAD + 4 * q]) = fr4[q];

        float g[NF];
#pragma unroll
        for (int u = 0; u < NF; ++u) g[u] = 0.f;

#pragma unroll
        for (int j = 0; j < 6; ++j) {
            const int k = q + 16 * j;
            float t = 0.f;
#pragma unroll
            for (int u = 0; u < NF; ++u) t += fr[u] * qreg[j][u];
            if (k < 85) row[pp * RPAD + 16 + k] = t;
#pragma unroll
            for (int u = 0; u < NF; ++u) g[u] += t * qreg[j][u];
        }

        // butterfly over the 16 q-lanes (lane bits 0..3)
#pragma unroll
        for (int m = 1; m <= 8; m <<= 1) {
#pragma unroll
            for (int u = 0; u < NF; ++u) g[u] += __shfl_xor(g[u], m);
        }
        row[pp * RPAD + 101 + q] = g[q];

        __syncthreads();
        // coalesced flush: 16 rows x 117 floats (b32, lanes contiguous)
        {
            float* dst = out + (size_t)(chunk + sb * 16) * NCOL;
            for (int t2 = tid; t2 < 16 * NCOL; t2 += 256) {
                const int r = t2 / NCOL;
                const int c = t2 - r * NCOL;
                dst[t2] = row[r * RPAD + c];
            }
        }
        __syncthreads();
    }
}

// ---------------------------------------------------------------------------
extern "C" void kernel_launch(void* const* d_in, const int* in_sizes, int n_in,
                              void* d_out, int out_size, void* d_ws, size_t ws_size,
                              hipStream_t stream)
{
    const float* X      = (const float*)d_in[0];
    const float* F      = (const float*)d_in[1];
    const float* QX     = (const float*)d_in[2];
    const float* omegaD = (const float*)d_in[3];
    const float* omegaF = (const float*)d_in[4];
    float* out = (float*)d_out;

    const int M = in_sizes[0] / 3;       // 262144
    const int K = in_sizes[3];           // 85
    const int nchunk = M / NPB;          // 8192

    int nb = (int)((ws_size / sizeof(float) - PBLK) / PBLK);
    if (nb > 256) nb = 256;              // 1 block/CU (12 waves)
    if (nb > nchunk) nb = nchunk;
    if (nb < 1) nb = 1;

    float* partial = (float*)d_ws;
    float* QFbuf   = partial + (size_t)nb * PBLK;

    hipLaunchKernelGGL(k1_partial, dim3(nb), dim3(768), 0, stream,
                       X, F, QX, omegaD, K, nchunk, partial);
    hipLaunchKernelGGL(k1_reduce, dim3(KP), dim3(256), 0, stream,
                       partial, omegaF, nb, QFbuf);
    hipLaunchKernelGGL(k2_out, dim3(M / 256), dim3(256), 0, stream,
                       F, QFbuf, out);
}

// Round 7
// 107.602 us; speedup vs baseline: 1.1719x; 1.1719x over previous
//
#include <hip/hip_runtime.h>

#define KP    96      // K=85 padded to 96 = 12 octets
#define NF    16
#define NCOL  117     // 16 + 85 + 16 output columns
#define RPAD  120     // LDS row stride
#define PBLK  (KP * NF)   // 1536 floats per partial block
#define NPB   32      // points per block-iteration (k1)

// ---------------------------------------------------------------------------
// Kernel 1: wave-per-k-octet partial QF accumulation. (UNCHANGED from R5.)
// ---------------------------------------------------------------------------
__global__ __launch_bounds__(768, 3) void k1_partial(
    const float* __restrict__ X, const float* __restrict__ F,
    const float* __restrict__ QX, const float* __restrict__ omegaD,
    int K, int nchunk, float* __restrict__ partial)
{
    __shared__ __align__(16) float red[12 * 2 * 64];   // 6 KB

    const int tid  = threadIdx.x;
    const int lane = tid & 63;
    const int oct  = __builtin_amdgcn_readfirstlane(tid >> 6);  // wave id 0..11
    const int fh   = lane >> 5;     // f-half
    const int pl   = lane & 31;     // point lane

    float4 qreg[8];
#pragma unroll
    for (int kk = 0; kk < 8; ++kk) {
        const int k = oct * 8 + kk;
        float4 v = make_float4(1.0e4f, 1.0e4f, 1.0e4f, -1.0f);  // pad -> e=0
        if (k < K) {
            v.x = QX[k * 3 + 0];
            v.y = QX[k * 3 + 1];
            v.z = QX[k * 3 + 2];
            const float w = omegaD[k];
            v.w = 1.0f / (w * w);
        }
        qreg[kk] = v;
    }

    float acc[8][8];
#pragma unroll
    for (int a2 = 0; a2 < 8; ++a2)
#pragma unroll
        for (int b2 = 0; b2 < 8; ++b2) acc[a2][b2] = 0.f;

    int pb = blockIdx.x;
    float x0 = 0.f, x1 = 0.f, x2 = 0.f;
    float4 fa = make_float4(0.f, 0.f, 0.f, 0.f), fb = fa;
    if (pb < nchunk) {
        const int p = pb * NPB + pl;
        x0 = X[p * 3 + 0]; x1 = X[p * 3 + 1]; x2 = X[p * 3 + 2];
        fa = *reinterpret_cast<const float4*>(&F[(size_t)p * NF + 8 * fh]);
        fb = *reinterpret_cast<const float4*>(&F[(size_t)p * NF + 8 * fh + 4]);
    }
    while (pb < nchunk) {
        const int pn = pb + gridDim.x;
        float nx0 = 0.f, nx1 = 0.f, nx2 = 0.f;
        float4 nfa = make_float4(0.f, 0.f, 0.f, 0.f), nfb = nfa;
        if (pn < nchunk) {
            const int p = pn * NPB + pl;
            nx0 = X[p * 3 + 0]; nx1 = X[p * 3 + 1]; nx2 = X[p * 3 + 2];
            nfa = *reinterpret_cast<const float4*>(&F[(size_t)p * NF + 8 * fh]);
            nfb = *reinterpret_cast<const float4*>(&F[(size_t)p * NF + 8 * fh + 4]);
        }

        float e[8];
#pragma unroll
        for (int kk = 0; kk < 8; ++kk) {
            const float4 q = qreg[kk];
            const float dx = x0 - q.x;
            const float dy = x1 - q.y;
            const float dz = x2 - q.z;
            e[kk] = __expf((dx * dx + dy * dy + dz * dz) * q.w);
        }
        const float fv[8] = {fa.x, fa.y, fa.z, fa.w, fb.x, fb.y, fb.z, fb.w};
#pragma unroll
        for (int kk = 0; kk < 8; ++kk)
#pragma unroll
            for (int u = 0; u < 8; ++u) acc[kk][u] += e[kk] * fv[u];

        x0 = nx0; x1 = nx1; x2 = nx2; fa = nfa; fb = nfb;
        pb = pn;
    }

#pragma unroll
    for (int m = 1; m <= 16; m <<= 1) {
#pragma unroll
        for (int a2 = 0; a2 < 8; ++a2)
#pragma unroll
            for (int b2 = 0; b2 < 8; ++b2)
                acc[a2][b2] += __shfl_xor(acc[a2][b2], m);
    }
    if (pl == 0) {
        float* rp = &red[oct * 128 + fh * 64];
#pragma unroll
        for (int a2 = 0; a2 < 8; ++a2) {
            *reinterpret_cast<float4*>(&rp[a2 * 8]) =
                make_float4(acc[a2][0], acc[a2][1], acc[a2][2], acc[a2][3]);
            *reinterpret_cast<float4*>(&rp[a2 * 8 + 4]) =
                make_float4(acc[a2][4], acc[a2][5], acc[a2][6], acc[a2][7]);
        }
    }
    __syncthreads();
    float* pbase = partial + (size_t)blockIdx.x * PBLK;
    for (int idx = tid; idx < PBLK; idx += 768) {
        const int o2 = idx >> 7;          // octet
        const int r  = idx & 127;
        const int kk = r >> 4;
        const int f  = r & 15;
        pbase[idx] = red[o2 * 128 + (f >> 3) * 64 + kk * 8 + (f & 7)];
    }
}

// ---------------------------------------------------------------------------
// Kernel 1.5: fixed-order reduction of partials -> QF (applies omegaF).
// (UNCHANGED.)
// ---------------------------------------------------------------------------
__global__ __launch_bounds__(256) void k1_reduce(
    const float* __restrict__ partial, const float* __restrict__ omegaF,
    int nb, float* __restrict__ QF)
{
    const int k   = blockIdx.x;
    const int tid = threadIdx.x;
    const int f = tid & 15, g = tid >> 4;
    float s = 0.f;
    for (int b = g; b < nb; b += 16)
        s += partial[(size_t)b * PBLK + k * NF + f];
    __shared__ float red[16][17];
    red[g][f] = s;
    __syncthreads();
    if (tid < 16) {
        float t = 0.f;
#pragma unroll
        for (int g2 = 0; g2 < 16; ++g2) t += red[g2][tid];
        QF[k * NF + tid] = t * omegaF[tid];
    }
}

// ---------------------------------------------------------------------------
// Kernel 1.75: B2 = QF^T @ QF  [16,16]. One block; thread (v,u) does an
// 85-step dot over QF columns v,u from LDS. Tiny.
// ---------------------------------------------------------------------------
__global__ __launch_bounds__(256) void k1_b2(
    const float* __restrict__ QF, float* __restrict__ B2)
{
    __shared__ float qf[85 * 16];
    const int tid = threadIdx.x;
    for (int i = tid; i < 85 * 16; i += 256) qf[i] = QF[i];
    __syncthreads();
    const int u = tid & 15, v = tid >> 4;
    float s = 0.f;
    for (int k = 0; k < 85; ++k) s += qf[k * 16 + v] * qf[k * 16 + u];
    B2[v * 16 + u] = s;
}

// ---------------------------------------------------------------------------
// Kernel 2 (FIXED): QF in registers, ZERO runtime-indexed local arrays.
// 256 threads = 32 k-lanes (q) x 8 points (pp). Lane q owns QF rows
// k = q + 32j (j<3, 48 VGPR, static indices only). Per point:
//   t_k = fr.qr[j]  -> LDS row buffer (b32, conflict-free)
//   lane q<16: g = fr . B2[:,q] (b2 column in 16 static registers) -> scalar
// Flush: cols 0..15 re-read F from global (L1-hot); cols 16.. from LDS.
// No shfl butterfly, no lane-indexed extracts.
// ---------------------------------------------------------------------------
__global__ __launch_bounds__(256, 3) void k2_out(
    const float* __restrict__ F, const float* __restrict__ QFb,
    const float* __restrict__ B2, float* __restrict__ out)
{
    __shared__ __align__(16) float row[8 * RPAD];   // 3.75 KB

    const int tid = threadIdx.x;
    const int q   = tid & 31;   // k-lane
    const int pp  = tid >> 5;   // point slot 0..7

    // lane q's QF rows: k = q + 32j, j = 0..2 (zero past K=85)
    float qr[3][NF];
#pragma unroll
    for (int j = 0; j < 3; ++j) {
        const int k = q + 32 * j;
        if (k < 85) {
            const float4* qv = reinterpret_cast<const float4*>(QFb + (size_t)k * NF);
#pragma unroll
            for (int u2 = 0; u2 < 4; ++u2) {
                const float4 t4 = qv[u2];
                qr[j][4 * u2 + 0] = t4.x; qr[j][4 * u2 + 1] = t4.y;
                qr[j][4 * u2 + 2] = t4.z; qr[j][4 * u2 + 3] = t4.w;
            }
        } else {
#pragma unroll
            for (int u2 = 0; u2 < NF; ++u2) qr[j][u2] = 0.f;
        }
    }
    // B2 column (q & 15): b2c[v] = B2[v][q&15]
    float b2c[NF];
#pragma unroll
    for (int v = 0; v < NF; ++v) b2c[v] = B2[v * 16 + (q & 15)];

    const int chunk = blockIdx.x * 256;

    for (int sb = 0; sb < 32; ++sb) {
        const int base = chunk + sb * 8;
        const int p = base + pp;

        float fr[NF];
        {
            const float4* Fv = reinterpret_cast<const float4*>(F + (size_t)p * NF);
#pragma unroll
            for (int u2 = 0; u2 < 4; ++u2) {
                const float4 t4 = Fv[u2];
                fr[4 * u2 + 0] = t4.x; fr[4 * u2 + 1] = t4.y;
                fr[4 * u2 + 2] = t4.z; fr[4 * u2 + 3] = t4.w;
            }
        }

        // t section: k = q + 32j
#pragma unroll
        for (int j = 0; j < 3; ++j) {
            const int k = q + 32 * j;
            float t = 0.f;
#pragma unroll
            for (int u2 = 0; u2 < NF; ++u2) t += fr[u2] * qr[j][u2];
            if (k < 85) row[pp * RPAD + 16 + k] = t;
        }
        // g section: lane q<16 computes the scalar g[q] = fr . B2[:,q]
        if (q < 16) {
            float g = 0.f;
#pragma unroll
            for (int v = 0; v < NF; ++v) g += fr[v] * b2c[v];
            row[pp * RPAD + 101 + q] = g;
        }

        __syncthreads();
        // flush 8 rows x 117 (coalesced b32); cols 0..15 straight from F
        {
            float* dst = out + (size_t)base * NCOL;
            for (int t2 = tid; t2 < 8 * NCOL; t2 += 256) {
                const int r = t2 / NCOL;
                const int c = t2 - r * NCOL;
                float v;
                if (c < 16) v = F[(size_t)(base + r) * NF + c];
                else        v = row[r * RPAD + c];
                dst[t2] = v;
            }
        }
        __syncthreads();
    }
}

// ---------------------------------------------------------------------------
extern "C" void kernel_launch(void* const* d_in, const int* in_sizes, int n_in,
                              void* d_out, int out_size, void* d_ws, size_t ws_size,
                              hipStream_t stream)
{
    const float* X      = (const float*)d_in[0];
    const float* F      = (const float*)d_in[1];
    const float* QX     = (const float*)d_in[2];
    const float* omegaD = (const float*)d_in[3];
    const float* omegaF = (const float*)d_in[4];
    float* out = (float*)d_out;

    const int M = in_sizes[0] / 3;       // 262144
    const int K = in_sizes[3];           // 85
    const int nchunk = M / NPB;          // 8192

    int nb = (int)((ws_size / sizeof(float) - PBLK - 256) / PBLK);
    if (nb > 256) nb = 256;              // 1 block/CU (12 waves)
    if (nb > nchunk) nb = nchunk;
    if (nb < 1) nb = 1;

    float* partial = (float*)d_ws;
    float* QFbuf   = partial + (size_t)nb * PBLK;
    float* B2buf   = QFbuf + PBLK;

    hipLaunchKernelGGL(k1_partial, dim3(nb), dim3(768), 0, stream,
                       X, F, QX, omegaD, K, nchunk, partial);
    hipLaunchKernelGGL(k1_reduce, dim3(KP), dim3(256), 0, stream,
                       partial, omegaF, nb, QFbuf);
    hipLaunchKernelGGL(k1_b2, dim3(1), dim3(256), 0, stream,
                       QFbuf, B2buf);
    hipLaunchKernelGGL(k2_out, dim3(M / 256), dim3(256), 0, stream,
                       F, QFbuf, B2buf, out);
}

// Round 8
// 77.493 us; speedup vs baseline: 1.6273x; 1.3885x over previous
//
#include <hip/hip_runtime.h>

#define KP    96      // K=85 padded to 96 = 12 octets
#define NF    16
#define NCOL  117     // 16 + 85 + 16 output columns
#define PBLK  (KP * NF)   // 1536 floats per partial block
#define NPB   32      // points per block-iteration (k1)

// ---------------------------------------------------------------------------
// Kernel 1: wave-per-k-octet partial QF accumulation. (UNCHANGED from R5.)
// ---------------------------------------------------------------------------
__global__ __launch_bounds__(768, 3) void k1_partial(
    const float* __restrict__ X, const float* __restrict__ F,
    const float* __restrict__ QX, const float* __restrict__ omegaD,
    int K, int nchunk, float* __restrict__ partial)
{
    __shared__ __align__(16) float red[12 * 2 * 64];   // 6 KB

    const int tid  = threadIdx.x;
    const int lane = tid & 63;
    const int oct  = __builtin_amdgcn_readfirstlane(tid >> 6);  // wave id 0..11
    const int fh   = lane >> 5;     // f-half
    const int pl   = lane & 31;     // point lane

    float4 qreg[8];
#pragma unroll
    for (int kk = 0; kk < 8; ++kk) {
        const int k = oct * 8 + kk;
        float4 v = make_float4(1.0e4f, 1.0e4f, 1.0e4f, -1.0f);  // pad -> e=0
        if (k < K) {
            v.x = QX[k * 3 + 0];
            v.y = QX[k * 3 + 1];
            v.z = QX[k * 3 + 2];
            const float w = omegaD[k];
            v.w = 1.0f / (w * w);
        }
        qreg[kk] = v;
    }

    float acc[8][8];
#pragma unroll
    for (int a2 = 0; a2 < 8; ++a2)
#pragma unroll
        for (int b2 = 0; b2 < 8; ++b2) acc[a2][b2] = 0.f;

    int pb = blockIdx.x;
    float x0 = 0.f, x1 = 0.f, x2 = 0.f;
    float4 fa = make_float4(0.f, 0.f, 0.f, 0.f), fb = fa;
    if (pb < nchunk) {
        const int p = pb * NPB + pl;
        x0 = X[p * 3 + 0]; x1 = X[p * 3 + 1]; x2 = X[p * 3 + 2];
        fa = *reinterpret_cast<const float4*>(&F[(size_t)p * NF + 8 * fh]);
        fb = *reinterpret_cast<const float4*>(&F[(size_t)p * NF + 8 * fh + 4]);
    }
    while (pb < nchunk) {
        const int pn = pb + gridDim.x;
        float nx0 = 0.f, nx1 = 0.f, nx2 = 0.f;
        float4 nfa = make_float4(0.f, 0.f, 0.f, 0.f), nfb = nfa;
        if (pn < nchunk) {
            const int p = pn * NPB + pl;
            nx0 = X[p * 3 + 0]; nx1 = X[p * 3 + 1]; nx2 = X[p * 3 + 2];
            nfa = *reinterpret_cast<const float4*>(&F[(size_t)p * NF + 8 * fh]);
            nfb = *reinterpret_cast<const float4*>(&F[(size_t)p * NF + 8 * fh + 4]);
        }

        float e[8];
#pragma unroll
        for (int kk = 0; kk < 8; ++kk) {
            const float4 q = qreg[kk];
            const float dx = x0 - q.x;
            const float dy = x1 - q.y;
            const float dz = x2 - q.z;
            e[kk] = __expf((dx * dx + dy * dy + dz * dz) * q.w);
        }
        const float fv[8] = {fa.x, fa.y, fa.z, fa.w, fb.x, fb.y, fb.z, fb.w};
#pragma unroll
        for (int kk = 0; kk < 8; ++kk)
#pragma unroll
            for (int u = 0; u < 8; ++u) acc[kk][u] += e[kk] * fv[u];

        x0 = nx0; x1 = nx1; x2 = nx2; fa = nfa; fb = nfb;
        pb = pn;
    }

#pragma unroll
    for (int m = 1; m <= 16; m <<= 1) {
#pragma unroll
        for (int a2 = 0; a2 < 8; ++a2)
#pragma unroll
            for (int b2 = 0; b2 < 8; ++b2)
                acc[a2][b2] += __shfl_xor(acc[a2][b2], m);
    }
    if (pl == 0) {
        float* rp = &red[oct * 128 + fh * 64];
#pragma unroll
        for (int a2 = 0; a2 < 8; ++a2) {
            *reinterpret_cast<float4*>(&rp[a2 * 8]) =
                make_float4(acc[a2][0], acc[a2][1], acc[a2][2], acc[a2][3]);
            *reinterpret_cast<float4*>(&rp[a2 * 8 + 4]) =
                make_float4(acc[a2][4], acc[a2][5], acc[a2][6], acc[a2][7]);
        }
    }
    __syncthreads();
    float* pbase = partial + (size_t)blockIdx.x * PBLK;
    for (int idx = tid; idx < PBLK; idx += 768) {
        const int o2 = idx >> 7;          // octet
        const int r  = idx & 127;
        const int kk = r >> 4;
        const int f  = r & 15;
        pbase[idx] = red[o2 * 128 + (f >> 3) * 64 + kk * 8 + (f & 7)];
    }
}

// ---------------------------------------------------------------------------
// Kernel 1.5: fixed-order reduction of partials -> QF (applies omegaF).
// (UNCHANGED.)
// ---------------------------------------------------------------------------
__global__ __launch_bounds__(256) void k1_reduce(
    const float* __restrict__ partial, const float* __restrict__ omegaF,
    int nb, float* __restrict__ QF)
{
    const int k   = blockIdx.x;
    const int tid = threadIdx.x;
    const int f = tid & 15, g = tid >> 4;
    float s = 0.f;
    for (int b = g; b < nb; b += 16)
        s += partial[(size_t)b * PBLK + k * NF + f];
    __shared__ float red[16][17];
    red[g][f] = s;
    __syncthreads();
    if (tid < 16) {
        float t = 0.f;
#pragma unroll
        for (int g2 = 0; g2 < 16; ++g2) t += red[g2][tid];
        QF[k * NF + tid] = t * omegaF[tid];
    }
}

// ---------------------------------------------------------------------------
// Kernel 1.75: B2 = QF^T @ QF  [16,16]. (UNCHANGED.)
// ---------------------------------------------------------------------------
__global__ __launch_bounds__(256) void k1_b2(
    const float* __restrict__ QF, float* __restrict__ B2)
{
    __shared__ float qf[85 * 16];
    const int tid = threadIdx.x;
    for (int i = tid; i < 85 * 16; i += 256) qf[i] = QF[i];
    __syncthreads();
    const int u = tid & 15, v = tid >> 4;
    float s = 0.f;
    for (int k = 0; k < 85; ++k) s += qf[k * 16 + v] * qf[k * 16 + u];
    B2[v * 16 + u] = s;
}

// ---------------------------------------------------------------------------
// Kernel 2 (RESTRUCTURED): 64-row LDS stages, 8 barriers/block total.
// 256 threads = 32 k-lanes (q) x 8 point-slots (pp). Lane q owns QF rows
// k = q + 32j (j<3, static indices). Per stage (64 points): 8 pipelined
// compute iterations fill row[64][117] (packed); then one contiguous
// float4 flush. F section: lane q==0, 16 static stores. g section: lane
// q<16, scalar g = fr.B2col. No runtime-indexed locals anywhere.
// ---------------------------------------------------------------------------
__global__ __launch_bounds__(256, 3) void k2_out(
    const float* __restrict__ F, const float* __restrict__ QFb,
    const float* __restrict__ B2, float* __restrict__ out)
{
    __shared__ __align__(16) float row[64 * NCOL];   // 29,952 B

    const int tid = threadIdx.x;
    const int q   = tid & 31;   // k-lane
    const int pp  = tid >> 5;   // point slot 0..7

    // lane q's QF rows: k = q + 32j, j = 0..2 (zero past K=85)
    float qr[3][NF];
#pragma unroll
    for (int j = 0; j < 3; ++j) {
        const int k = q + 32 * j;
        if (k < 85) {
            const float4* qv = reinterpret_cast<const float4*>(QFb + (size_t)k * NF);
#pragma unroll
            for (int u2 = 0; u2 < 4; ++u2) {
                const float4 t4 = qv[u2];
                qr[j][4 * u2 + 0] = t4.x; qr[j][4 * u2 + 1] = t4.y;
                qr[j][4 * u2 + 2] = t4.z; qr[j][4 * u2 + 3] = t4.w;
            }
        } else {
#pragma unroll
            for (int u2 = 0; u2 < NF; ++u2) qr[j][u2] = 0.f;
        }
    }
    // B2 column (q & 15): b2c[v] = B2[v][q&15]
    float b2c[NF];
#pragma unroll
    for (int v = 0; v < NF; ++v) b2c[v] = B2[v * 16 + (q & 15)];

    const int chunk = blockIdx.x * 256;

    for (int st = 0; st < 4; ++st) {
        const int sbase = chunk + st * 64;

        // pipelined fill of row[64][117]
        float fr[NF];
        {
            const float4* Fv = reinterpret_cast<const float4*>(F + (size_t)(sbase + pp) * NF);
            const float4 t0 = Fv[0], t1 = Fv[1], t2 = Fv[2], t3 = Fv[3];
            fr[0]  = t0.x; fr[1]  = t0.y; fr[2]  = t0.z; fr[3]  = t0.w;
            fr[4]  = t1.x; fr[5]  = t1.y; fr[6]  = t1.z; fr[7]  = t1.w;
            fr[8]  = t2.x; fr[9]  = t2.y; fr[10] = t2.z; fr[11] = t2.w;
            fr[12] = t3.x; fr[13] = t3.y; fr[14] = t3.z; fr[15] = t3.w;
        }
#pragma unroll
        for (int it = 0; it < 8; ++it) {
            float4 n0, n1, n2, n3;
            if (it < 7) {
                const float4* Fv = reinterpret_cast<const float4*>(
                    F + (size_t)(sbase + (it + 1) * 8 + pp) * NF);
                n0 = Fv[0]; n1 = Fv[1]; n2 = Fv[2]; n3 = Fv[3];
            }
            float* rp = &row[(it * 8 + pp) * NCOL];
            // t section: k = q + 32j
#pragma unroll
            for (int j = 0; j < 3; ++j) {
                const int k = q + 32 * j;
                float t = 0.f;
#pragma unroll
                for (int u2 = 0; u2 < NF; ++u2) t += fr[u2] * qr[j][u2];
                if (k < 85) rp[16 + k] = t;
            }
            // F section: lane q==0, static indices
            if (q == 0) {
#pragma unroll
                for (int u2 = 0; u2 < NF; ++u2) rp[u2] = fr[u2];
            }
            // g section: lane q<16, scalar
            if (q < 16) {
                float g = 0.f;
#pragma unroll
                for (int v = 0; v < NF; ++v) g += fr[v] * b2c[v];
                rp[101 + q] = g;
            }
            if (it < 7) {
                fr[0]  = n0.x; fr[1]  = n0.y; fr[2]  = n0.z; fr[3]  = n0.w;
                fr[4]  = n1.x; fr[5]  = n1.y; fr[6]  = n1.z; fr[7]  = n1.w;
                fr[8]  = n2.x; fr[9]  = n2.y; fr[10] = n2.z; fr[11] = n2.w;
                fr[12] = n3.x; fr[13] = n3.y; fr[14] = n3.z; fr[15] = n3.w;
            }
        }

        __syncthreads();
        // contiguous flush: 64*117 floats = 1872 float4
        {
            float4* dst = reinterpret_cast<float4*>(out + (size_t)sbase * NCOL);
            const float4* src = reinterpret_cast<const float4*>(row);
            for (int t2 = tid; t2 < (64 * NCOL) / 4; t2 += 256) dst[t2] = src[t2];
        }
        __syncthreads();
    }
}

// ---------------------------------------------------------------------------
extern "C" void kernel_launch(void* const* d_in, const int* in_sizes, int n_in,
                              void* d_out, int out_size, void* d_ws, size_t ws_size,
                              hipStream_t stream)
{
    const float* X      = (const float*)d_in[0];
    const float* F      = (const float*)d_in[1];
    const float* QX     = (const float*)d_in[2];
    const float* omegaD = (const float*)d_in[3];
    const float* omegaF = (const float*)d_in[4];
    float* out = (float*)d_out;

    const int M = in_sizes[0] / 3;       // 262144
    const int K = in_sizes[3];           // 85
    const int nchunk = M / NPB;          // 8192

    int nb = (int)((ws_size / sizeof(float) - PBLK - 256) / PBLK);
    if (nb > 256) nb = 256;              // 1 block/CU (12 waves)
    if (nb > nchunk) nb = nchunk;
    if (nb < 1) nb = 1;

    float* partial = (float*)d_ws;
    float* QFbuf   = partial + (size_t)nb * PBLK;
    float* B2buf   = QFbuf + PBLK;

    hipLaunchKernelGGL(k1_partial, dim3(nb), dim3(768), 0, stream,
                       X, F, QX, omegaD, K, nchunk, partial);
    hipLaunchKernelGGL(k1_reduce, dim3(KP), dim3(256), 0, stream,
                       partial, omegaF, nb, QFbuf);
    hipLaunchKernelGGL(k1_b2, dim3(1), dim3(256), 0, stream,
                       QFbuf, B2buf);
    hipLaunchKernelGGL(k2_out, dim3(M / 256), dim3(256), 0, stream,
                       F, QFbuf, B2buf, out);
}